// Round 10
// baseline (161.973 us; speedup 1.0000x reference)
//
#include <hip/hip_runtime.h>
#include <stdint.h>

#define B_ 8
#define C_ 256
#define H_ 96
#define W_ 160
#define ND 9
#define NDISP 81
#define CK 2                   // channels per chunk
#define NCHUNK (C_ / CK)       // 128
#define TX 8
#define NXG (W_ / TX)          // 20
#define NTHR 192               // 3 waves
#define NCOMP (ND * NXG)       // 180 compute threads
#define ROWS_PER_CH 9          // in2 rows only; in1 goes global->reg
#define NROWS (CK * ROWS_PER_CH)  // 18
// INVARIANT: row stride must be a multiple of the 16B DMA width (R8 lesson).
#define STRF 172               // floats per row slot (688 B = 43*16)
#define ROWB 688
#define BUF_B 13312            // 13 x 1024B DMA slots (>= 18*688=12384); %512==0
#define BUF_F 3328
#define NBUF 2                 // depth-1 (R6: depth is not the gate); 26624 B
#define CHSTEP (CK * H_ * W_)  // global float step per chunk

typedef const __attribute__((address_space(1))) void GV;
typedef __attribute__((address_space(3))) void LV;
#define DMA16(g, l) __builtin_amdgcn_global_load_lds((GV*)(g), (LV*)(l), 16, 0, 0)

// 32B-stride lanes repeat bank classes every 128 B (addr bits 7-8) -> XOR
// those into bank bits 4-5. Involution within 512B windows, 16B-preserving.
__device__ __forceinline__ int swz(int o) { return o ^ (((o >> 7) & 3) << 4); }

// Map a physical LDS byte offset O to its in2 source (pre-swizzled source:
// LDS[O] holds logical data swz(O); readers use swz(logical)).
__device__ __forceinline__ const float* decode_src(int O, int b, int y,
        const float* in1, const float* in2)
{
    const int Os = swz(O);
    const int R  = Os / ROWB;
    const int xb = Os - R * ROWB;          // 16-aligned (ROWB%16==0)
    if (R >= NROWS) return in1;            // dummy slot tail, never read logically
    const int ch = R / ROWS_PER_CH;
    const int r  = R - ch * ROWS_PER_CH;   // dy
    int row = y + r - 4;
    row = row < 0 ? 0 : (row >= H_ ? H_ - 1 : row);  // clamped; masked later
    // xb<640: read [xb,xb+16) ends <= 640 = real row bytes -> never OOB.
    const int xo = (xb < 640) ? (xb >> 2) : 0;       // row pad -> dummy
    return in2 + ((size_t)(b * C_ + ch) * H_ + row) * W_ + xo;
}

__global__ __launch_bounds__(NTHR) void corr4_kernel(
    const float* __restrict__ in1,
    const float* __restrict__ in2,
    float* __restrict__ out)
{
    __shared__ float lds[NBUF * BUF_F];   // 26624 B -> ~5 blocks/CU capacity

    const int tid  = threadIdx.x;
    const int b    = blockIdx.x & 7;      // XCD swizzle: batch pinned to XCD
    const int y    = blockIdx.x >> 3;
    const int lane = tid & 63;
    const int wv   = tid >> 6;            // 0..2; wave wv owns slots wv+3k

    // ---- per-lane DMA sources (wave0: 5 slots, wave1/2: 4; vmcnt(0) drain
    // discipline makes uneven counts legal)
    const float* g0 = decode_src((wv + 0) * 1024 + lane * 16, b, y, in1, in2);
    const float* g1 = decode_src((wv + 3) * 1024 + lane * 16, b, y, in1, in2);
    const float* g2 = decode_src((wv + 6) * 1024 + lane * 16, b, y, in1, in2);
    const float* g3 = decode_src((wv + 9) * 1024 + lane * 16, b, y, in1, in2);
    const float* g4 = decode_src((wv == 0 ? 12 * 1024 : 13 * 1024) + lane * 16,
                                 b, y, in1, in2);   // wv!=0 -> dummy decode

    // ---- compute coords: dy-major (lanes 0-19 = dy0 ... -> a-addr broadcast)
    const bool isComp = (tid < NCOMP);
    const int  dy = tid / NXG;            // 0..8
    const int  xg = tid % NXG;            // 0..19
    const int  x0 = xg * TX;
    const bool rowOk = isComp && (y + dy - 4 >= 0) && (y + dy - 4 < H_);

    // ---- in1 direct-global pointer (L1/L2-served; 3-way same-addr in wave)
    const float* ap = in1 + ((size_t)(b * C_) * H_ + y) * W_ + x0;

    // ---- swizzled w-read offsets (bytes, buffer-local)
    const int wb0 = ((0 * ROWS_PER_CH + dy) * STRF + x0 - 4) * 4;
    const int wb1 = ((1 * ROWS_PER_CH + dy) * STRF + x0 - 4) * 4;
    const int wof00 = swz(xg == 0 ? wb0 + 16 : wb0);   // avoid underflow; masked
    const int wof01 = swz(wb0 + 16);
    const int wof02 = swz(wb0 + 32), wof03 = swz(wb0 + 48);
    const int wof10 = swz(xg == 0 ? wb1 + 16 : wb1);
    const int wof11 = swz(wb1 + 16);
    const int wof12 = swz(wb1 + 32), wof13 = swz(wb1 + 48);

    float acc[ND][TX];
    #pragma unroll
    for (int dx = 0; dx < ND; ++dx)
        #pragma unroll
        for (int j = 0; j < TX; ++j) acc[dx][j] = 0.f;

    #define ISSUE(BUFI) do {                                                  \
        float* lb = &lds[(BUFI) * BUF_F];                                     \
        DMA16(g0, lb + (wv + 0) * 256);                                       \
        DMA16(g1, lb + (wv + 3) * 256);                                       \
        DMA16(g2, lb + (wv + 6) * 256);                                       \
        DMA16(g3, lb + (wv + 9) * 256);                                       \
        if (wv == 0) DMA16(g4, lb + 12 * 256);                                \
        g0 += CHSTEP; g1 += CHSTEP; g2 += CHSTEP; g3 += CHSTEP; g4 += CHSTEP; \
    } while (0);

    #define FMACH(A0, A1, W0, W1, W2, W3) {                                   \
        float4 w0v = (W0), w3v = (W3);                                        \
        if (xg == 0)       w0v = make_float4(0.f, 0.f, 0.f, 0.f);             \
        if (xg == NXG - 1) w3v = make_float4(0.f, 0.f, 0.f, 0.f);             \
        float a[8]  = {(A0).x, (A0).y, (A0).z, (A0).w,                        \
                       (A1).x, (A1).y, (A1).z, (A1).w};                       \
        float w[16] = {w0v.x, w0v.y, w0v.z, w0v.w,                            \
                       (W1).x, (W1).y, (W1).z, (W1).w,                        \
                       (W2).x, (W2).y, (W2).z, (W2).w,                        \
                       w3v.x, w3v.y, w3v.z, w3v.w};                           \
        _Pragma("unroll")                                                     \
        for (int dx = 0; dx < ND; ++dx) {                                     \
            _Pragma("unroll")                                                 \
            for (int j = 0; j < TX; ++j)                                      \
                acc[dx][j] += a[j] * w[dx + j];                               \
        }                                                                     \
    }

    #define COMPUTE(BUFI)                                                     \
    if (isComp) {                                                             \
        const char* bb = (const char*)lds + (BUFI) * BUF_B;                   \
        float4 a0c0 = *(const float4*)(ap);                                   \
        float4 a1c0 = *(const float4*)(ap + 4);                               \
        float4 a0c1 = *(const float4*)(ap + H_ * W_);                         \
        float4 a1c1 = *(const float4*)(ap + H_ * W_ + 4);                     \
        {                                                                     \
            float4 w0 = *(const float4*)(bb + wof00);                         \
            float4 w1 = *(const float4*)(bb + wof01);                         \
            float4 w2 = *(const float4*)(bb + wof02);                         \
            float4 w3 = *(const float4*)(bb + wof03);                         \
            FMACH(a0c0, a1c0, w0, w1, w2, w3)                                 \
        }                                                                     \
        {                                                                     \
            float4 w0 = *(const float4*)(bb + wof10);                         \
            float4 w1 = *(const float4*)(bb + wof11);                         \
            float4 w2 = *(const float4*)(bb + wof12);                         \
            float4 w3 = *(const float4*)(bb + wof13);                         \
            FMACH(a0c1, a1c1, w0, w1, w2, w3)                                 \
        }                                                                     \
        ap += CHSTEP;                                                         \
    }

    // ---- prologue: DMA chunk 0 into buffer 0
    ISSUE(0)

    // ---- main loop: depth-1 dbuf; full drain (uneven slot counts safe)
    #pragma unroll 1
    for (int kc = 0; kc < NCHUNK; ++kc) {
        asm volatile("s_waitcnt vmcnt(0)" ::: "memory");   // chunk kc landed
        __builtin_amdgcn_s_barrier();                      // + readers of kc-1 done
        asm volatile("" ::: "memory");
        __builtin_amdgcn_sched_barrier(0);
        if (kc + 1 < NCHUNK) ISSUE((kc + 1) & 1);
        COMPUTE(kc & 1)
    }

    #undef COMPUTE
    #undef FMACH
    #undef ISSUE

    // ---- epilogue: OOB-dy rows output zeros (masked scale; staged garbage
    // was clamped real data -> finite, so 0-scale is exact)
    if (isComp) {
        const float m = rowOk ? (1.0f / (float)C_) : 0.f;
        float* outp = out + ((size_t)(b * NDISP + dy * ND) * H_ + y) * W_ + x0;
        #pragma unroll
        for (int dx = 0; dx < ND; ++dx) {
            float4 o0 = make_float4(acc[dx][0] * m, acc[dx][1] * m,
                                    acc[dx][2] * m, acc[dx][3] * m);
            float4 o1 = make_float4(acc[dx][4] * m, acc[dx][5] * m,
                                    acc[dx][6] * m, acc[dx][7] * m);
            *(float4*)(outp + dx * (H_ * W_))     = o0;
            *(float4*)(outp + dx * (H_ * W_) + 4) = o1;
        }
    }
}

extern "C" void kernel_launch(void* const* d_in, const int* in_sizes, int n_in,
                              void* d_out, int out_size, void* d_ws, size_t ws_size,
                              hipStream_t stream) {
    const float* in1 = (const float*)d_in[0];
    const float* in2 = (const float*)d_in[1];
    float* out = (float*)d_out;

    const int grid = B_ * H_;   // 768 blocks; ~5/CU capacity, 3 avg resident
    corr4_kernel<<<grid, NTHR, 0, stream>>>(in1, in2, out);
}

// Round 11
// 143.078 us; speedup vs baseline: 1.1321x; 1.1321x over previous
//
#include <hip/hip_runtime.h>
#include <stdint.h>

#define B_ 8
#define C_ 256
#define H_ 96
#define W_ 160
#define ND 9
#define NDISP 81
#define CK 2                   // channels per chunk
#define NCHUNK (C_ / CK)       // 128
#define TX 8
#define NXG (W_ / TX)          // 20
#define NTHR 64                // ONE wave per block -> no barriers at all
#define DYB 3                  // dy values per block
#define NCOMP (DYB * NXG)      // 60 compute lanes
#define ROWS_PER_CH 4          // 1 in1 row + 3 in2 rows
#define NROWS (CK * ROWS_PER_CH)  // 8
// INVARIANT: row stride multiple of 16B DMA width (R8 lesson).
#define STRF 172               // floats per row slot (688 B = 43*16)
#define ROWB 688
#define BUF_B 6144             // 6 x 1024B DMA slots (>= 8*688=5504); %512==0
#define BUF_F 1536
#define NBUF 2                 // 12288 B/block -> 9+ single-wave blocks/CU
#define CHSTEP (CK * H_ * W_)  // global float step per chunk

typedef const __attribute__((address_space(1))) void GV;
typedef __attribute__((address_space(3))) void LV;
#define DMA16(g, l) __builtin_amdgcn_global_load_lds((GV*)(g), (LV*)(l), 16, 0, 0)

// 32B-stride lanes repeat bank classes every 128 B (addr bits 7-8) -> XOR
// those into bank bits 4-5. Involution within 512B windows, 16B-preserving.
__device__ __forceinline__ int swz(int o) { return o ^ (((o >> 7) & 3) << 4); }

// Map a physical LDS byte offset O to its global source (pre-swizzled source:
// LDS[O] holds logical data swz(O); readers use swz(logical)).
__device__ __forceinline__ const float* decode_src(int O, int b, int y, int dyg,
        const float* in1, const float* in2)
{
    const int Os = swz(O);
    const int R  = Os / ROWB;
    const int xb = Os - R * ROWB;          // 16-aligned (ROWB%16==0)
    if (R >= NROWS) return in1;            // dummy slot tail, never read logically
    const int ch = R >> 2;                 // ROWS_PER_CH == 4
    const int r  = R & 3;
    const float* basep;
    int row;
    if (r == 0) { basep = in1; row = y; }  // in1 row y
    else {                                 // in2 row y + dyg*3 + (r-1) - 4
        row = y + dyg * 3 + (r - 1) - 4;
        row = row < 0 ? 0 : (row >= H_ ? H_ - 1 : row);  // clamped; masked later
        basep = in2;
    }
    // xb<640: read [xb,xb+16) ends <= 640 = real row bytes -> never OOB.
    const int xo = (xb < 640) ? (xb >> 2) : 0;           // row pad -> dummy
    return basep + ((size_t)(b * C_ + ch) * H_ + row) * W_ + xo;
}

__global__ __launch_bounds__(NTHR) void corr1w_kernel(
    const float* __restrict__ in1,
    const float* __restrict__ in2,
    float* __restrict__ out)
{
    __shared__ float lds[NBUF * BUF_F];   // 12288 B, never zero-inited

    const int tid  = threadIdx.x;
    const int b    = blockIdx.x & 7;      // XCD swizzle: batch pinned to XCD
    const int idx  = blockIdx.x >> 3;     // 0..287
    const int y    = idx / 3;
    const int dyg  = idx % 3;             // dy group: dy = dyg*3 + dyl
    const int lane = tid;                 // single wave

    // ---- per-lane DMA sources: 6 slots, all owned by this wave
    const float* g0 = decode_src(0 * 1024 + lane * 16, b, y, dyg, in1, in2);
    const float* g1 = decode_src(1 * 1024 + lane * 16, b, y, dyg, in1, in2);
    const float* g2 = decode_src(2 * 1024 + lane * 16, b, y, dyg, in1, in2);
    const float* g3 = decode_src(3 * 1024 + lane * 16, b, y, dyg, in1, in2);
    const float* g4 = decode_src(4 * 1024 + lane * 16, b, y, dyg, in1, in2);
    const float* g5 = decode_src(5 * 1024 + lane * 16, b, y, dyg, in1, in2);

    // ---- compute coords (lanes 0-59): dyl-major
    const bool isComp = (tid < NCOMP);
    const int  dyl = tid / NXG;           // 0..2
    const int  xg  = tid % NXG;           // 0..19
    const int  x0  = xg * TX;
    const int  dy  = dyg * 3 + dyl;       // global displacement row 0..8
    const bool rowOk = isComp && (y + dy - 4 >= 0) && (y + dy - 4 < H_);

    // ---- swizzled read offsets (bytes, buffer-local)
    // row layout per buffer: [c*4 + 0]=in1, [c*4 + 1 + dyl]=in2(dyl)
    const int ab0 = ((0 * ROWS_PER_CH) * STRF + x0) * 4;
    const int ab1 = ((1 * ROWS_PER_CH) * STRF + x0) * 4;
    const int wb0 = ((0 * ROWS_PER_CH + 1 + dyl) * STRF + x0 - 4) * 4;  // >= 672
    const int wb1 = ((1 * ROWS_PER_CH + 1 + dyl) * STRF + x0 - 4) * 4;
    const int aof00 = swz(ab0), aof01 = swz(ab0 + 16);
    const int aof10 = swz(ab1), aof11 = swz(ab1 + 16);
    const int wof00 = swz(wb0),      wof01 = swz(wb0 + 16);
    const int wof02 = swz(wb0 + 32), wof03 = swz(wb0 + 48);
    const int wof10 = swz(wb1),      wof11 = swz(wb1 + 16);
    const int wof12 = swz(wb1 + 32), wof13 = swz(wb1 + 48);

    float acc[ND][TX];
    #pragma unroll
    for (int dx = 0; dx < ND; ++dx)
        #pragma unroll
        for (int j = 0; j < TX; ++j) acc[dx][j] = 0.f;

    #define ISSUE(BUFI) do {                                                  \
        float* lb = &lds[(BUFI) * BUF_F];                                     \
        DMA16(g0, lb + 0 * 256);                                              \
        DMA16(g1, lb + 1 * 256);                                              \
        DMA16(g2, lb + 2 * 256);                                              \
        DMA16(g3, lb + 3 * 256);                                              \
        DMA16(g4, lb + 4 * 256);                                              \
        DMA16(g5, lb + 5 * 256);                                              \
        g0 += CHSTEP; g1 += CHSTEP; g2 += CHSTEP;                             \
        g3 += CHSTEP; g4 += CHSTEP; g5 += CHSTEP;                             \
    } while (0);

    #define FMACH(A0, A1, W0, W1, W2, W3) {                                   \
        float4 w0v = (W0), w3v = (W3);                                        \
        if (xg == 0)       w0v = make_float4(0.f, 0.f, 0.f, 0.f);             \
        if (xg == NXG - 1) w3v = make_float4(0.f, 0.f, 0.f, 0.f);             \
        float a[8]  = {(A0).x, (A0).y, (A0).z, (A0).w,                        \
                       (A1).x, (A1).y, (A1).z, (A1).w};                       \
        float w[16] = {w0v.x, w0v.y, w0v.z, w0v.w,                            \
                       (W1).x, (W1).y, (W1).z, (W1).w,                        \
                       (W2).x, (W2).y, (W2).z, (W2).w,                        \
                       w3v.x, w3v.y, w3v.z, w3v.w};                           \
        _Pragma("unroll")                                                     \
        for (int dx = 0; dx < ND; ++dx) {                                     \
            _Pragma("unroll")                                                 \
            for (int j = 0; j < TX; ++j)                                      \
                acc[dx][j] += a[j] * w[dx + j];                               \
        }                                                                     \
    }

    #define COMPUTE(BUFI)                                                     \
    if (isComp) {                                                             \
        const char* bb = (const char*)lds + (BUFI) * BUF_B;                   \
        {                                                                     \
            float4 a0 = *(const float4*)(bb + aof00);                         \
            float4 a1 = *(const float4*)(bb + aof01);                         \
            float4 w0 = *(const float4*)(bb + wof00);                         \
            float4 w1 = *(const float4*)(bb + wof01);                         \
            float4 w2 = *(const float4*)(bb + wof02);                         \
            float4 w3 = *(const float4*)(bb + wof03);                         \
            FMACH(a0, a1, w0, w1, w2, w3)                                     \
        }                                                                     \
        {                                                                     \
            float4 a0 = *(const float4*)(bb + aof10);                         \
            float4 a1 = *(const float4*)(bb + aof11);                         \
            float4 w0 = *(const float4*)(bb + wof10);                         \
            float4 w1 = *(const float4*)(bb + wof11);                         \
            float4 w2 = *(const float4*)(bb + wof12);                         \
            float4 w3 = *(const float4*)(bb + wof13);                         \
            FMACH(a0, a1, w0, w1, w2, w3)                                     \
        }                                                                     \
    }

    // body kc (wave-local, NO barrier):
    //   vmcnt(6): chunk kc's 6 DMAs (issued in body kc-2) have committed to
    //   LDS; kc+1's 6 remain outstanding. COMPUTE(kc&1). lgkmcnt(0): own
    //   ds_reads retired -> safe to DMA-overwrite this buffer with kc+2.
    #define BODY(BUFI, WN, DOISS)                                             \
        asm volatile("s_waitcnt vmcnt(" WN ")" ::: "memory");                 \
        __builtin_amdgcn_sched_barrier(0);                                    \
        COMPUTE(BUFI)                                                         \
        asm volatile("s_waitcnt lgkmcnt(0)" ::: "memory");                    \
        __builtin_amdgcn_sched_barrier(0);                                    \
        if (DOISS) { ISSUE(BUFI) }

    // ---- prologue: DMA chunks 0,1 into buffers 0,1 (12 outstanding)
    ISSUE(0)
    ISSUE(1)

    // ---- main loop: kc = 0..125 (body kc issues kc+2 into buffer kc&1)
    #pragma unroll 1
    for (int g = 0; g < 63; ++g) {
        BODY(0, "6", true)
        BODY(1, "6", true)
    }
    // ---- tail: kc = 126 (127 outstanding), kc = 127
    BODY(0, "6", false)
    BODY(1, "0", false)

    #undef BODY
    #undef COMPUTE
    #undef FMACH
    #undef ISSUE

    // ---- epilogue: OOB-dy rows output zeros (masked scale; staged garbage
    // was clamped real data -> finite, so 0-scale is exact)
    if (isComp) {
        const float m = rowOk ? (1.0f / (float)C_) : 0.f;
        float* outp = out + ((size_t)(b * NDISP + dy * ND) * H_ + y) * W_ + x0;
        #pragma unroll
        for (int dx = 0; dx < ND; ++dx) {
            float4 o0 = make_float4(acc[dx][0] * m, acc[dx][1] * m,
                                    acc[dx][2] * m, acc[dx][3] * m);
            float4 o1 = make_float4(acc[dx][4] * m, acc[dx][5] * m,
                                    acc[dx][6] * m, acc[dx][7] * m);
            *(float4*)(outp + dx * (H_ * W_))     = o0;
            *(float4*)(outp + dx * (H_ * W_) + 4) = o1;
        }
    }
}

extern "C" void kernel_launch(void* const* d_in, const int* in_sizes, int n_in,
                              void* d_out, int out_size, void* d_ws, size_t ws_size,
                              hipStream_t stream) {
    const float* in1 = (const float*)d_in[0];
    const float* in2 = (const float*)d_in[1];
    float* out = (float*)d_out;

    const int grid = B_ * H_ * 3;   // 2304 single-wave blocks = 9 per CU
    corr1w_kernel<<<grid, NTHR, 0, stream>>>(in1, in2, out);
}

// Round 12
// 141.015 us; speedup vs baseline: 1.1486x; 1.0146x over previous
//
#include <hip/hip_runtime.h>
#include <stdint.h>

#define B_ 8
#define C_ 256
#define H_ 96
#define W_ 160
#define ND 9
#define NDISP 81
#define CK 2                   // channels per chunk
#define NCHUNK (C_ / CK)       // 128
#define TX 4
#define NXG 20                 // x-groups per half (half-width 80 = 20*4)
#define NTHR 64                // ONE wave per block, no barriers
#define NCOMP 60               // 3 dyl * 20 xg
// LDS chunk layout (bytes), per channel c at CH_B*c:
//   in1 row: 320 B = 80 floats, global x [80h, 80h+80)
//   in2 rows dyl=0..2: 400 B each = 100 floats, global x [80h-4, 80h+96)
// ROW_B=400 -> 25 16B-blocks == 1 (mod 8 bank-groups): the 3 dyl groups read
// bank-group patterns offset by +1 -> near-balanced, no swizzle needed.
#define IN1_B 320
#define ROW_B 400
#define CH_B  1520             // 320 + 3*400
#define CHUNK_B 3040           // 2 channels
#define BUF_B 3072             // 3 x 1024B DMA slots; INVARIANT: rows 16B-mult
#define BUF_F 768
#define NBUF 2                 // 6144 B/block -> LDS allows 26 blocks/CU
#define CHSTEP (CK * H_ * W_)  // global float step per chunk

typedef const __attribute__((address_space(1))) void GV;
typedef __attribute__((address_space(3))) void LV;
#define DMA16(g, l) __builtin_amdgcn_global_load_lds((GV*)(g), (LV*)(l), 16, 0, 0)

// Map physical LDS byte offset O (linear, no swizzle) to its global source.
// Clamped positions hold garbage that is masked in the FMA stage.
__device__ __forceinline__ const float* decode_src(int O, int b, int y,
        int dyg, int h, const float* in1, const float* in2)
{
    if (O >= CHUNK_B) O = CH_B;            // slot-2 tail dummy (never read)
    const int ch  = O / CH_B;
    const int rem = O - ch * CH_B;
    const float* basep;
    int row, x;
    if (rem < IN1_B) {                     // in1 row y
        basep = in1; row = y; x = 80 * h + (rem >> 2);
    } else {
        const int r  = (rem - IN1_B) / ROW_B;          // dyl 0..2
        const int fb = (rem - IN1_B) - r * ROW_B;
        basep = in2;
        row = y + dyg * 3 + r - 4;
        row = row < 0 ? 0 : (row >= H_ ? H_ - 1 : row);  // clamp; masked later
        x = 80 * h - 4 + (fb >> 2);
        x = x < 0 ? 0 : (x > W_ - TX ? W_ - TX : x);     // clamp; masked later
    }
    return basep + ((size_t)(b * C_ + ch) * H_ + row) * W_ + x;  // 16B-aligned
}

__global__ __launch_bounds__(NTHR) void corr_hx_kernel(
    const float* __restrict__ in1,
    const float* __restrict__ in2,
    float* __restrict__ out)
{
    __shared__ float lds[NBUF * BUF_F];   // 6144 B, never zero-inited

    const int tid = threadIdx.x;
    const int b   = blockIdx.x & 7;       // XCD swizzle: batch pinned to XCD
    const int idx = blockIdx.x >> 3;      // 0..575
    const int y   = idx / 6;
    const int t6  = idx % 6;
    const int dyg = t6 >> 1;              // 0..2 (dy = dyg*3 + dyl)
    const int h   = t6 & 1;               // x half

    // ---- per-lane DMA sources: 3 slots, all owned by this wave
    const float* g0 = decode_src(0 * 1024 + tid * 16, b, y, dyg, h, in1, in2);
    const float* g1 = decode_src(1 * 1024 + tid * 16, b, y, dyg, h, in1, in2);
    const float* g2 = decode_src(2 * 1024 + tid * 16, b, y, dyg, h, in1, in2);

    // ---- compute coords (lanes 0-59): dyl-major
    const bool isComp = (tid < NCOMP);
    const int  dyl = tid / NXG;           // 0..2
    const int  xg  = tid % NXG;           // 0..19
    const int  x0  = 80 * h + TX * xg;
    const int  dy  = dyg * 3 + dyl;       // 0..8
    const bool rowOk = isComp && (y + dy - 4 >= 0) && (y + dy - 4 < H_);
    // full-float4 edge masks (zero-pad in x):
    const bool mzW0 = (h == 0) && (xg == 0);        // w0 = x [-4,0)
    const bool mzW2 = (h == 1) && (xg == NXG - 1);  // w2 = x [160,164)

    // ---- read offsets (bytes, buffer-local, linear)
    const int aof0 = 16 * xg;                               // ch0 in1
    const int aof1 = CH_B + 16 * xg;                        // ch1 in1
    const int wb0  = IN1_B + dyl * ROW_B + 16 * xg;         // ch0 in2: f=4xg
    const int wb1  = CH_B + IN1_B + dyl * ROW_B + 16 * xg;  // ch1 in2

    float acc[ND][TX];
    #pragma unroll
    for (int dx = 0; dx < ND; ++dx)
        #pragma unroll
        for (int j = 0; j < TX; ++j) acc[dx][j] = 0.f;

    #define ISSUE(BUFI) do {                                                  \
        float* lb = &lds[(BUFI) * BUF_F];                                     \
        DMA16(g0, lb);                                                        \
        DMA16(g1, lb + 256);                                                  \
        DMA16(g2, lb + 512);                                                  \
        g0 += CHSTEP; g1 += CHSTEP; g2 += CHSTEP;                             \
    } while (0);

    #define FMACH(AOF, WB) {                                                  \
        float4 a4 = *(const float4*)(bb + (AOF));                             \
        float4 w0 = *(const float4*)(bb + (WB));                              \
        float4 w1 = *(const float4*)(bb + (WB) + 16);                         \
        float4 w2 = *(const float4*)(bb + (WB) + 32);                         \
        if (mzW0) w0 = make_float4(0.f, 0.f, 0.f, 0.f);                       \
        if (mzW2) w2 = make_float4(0.f, 0.f, 0.f, 0.f);                       \
        float a[4]  = {a4.x, a4.y, a4.z, a4.w};                               \
        float w[12] = {w0.x, w0.y, w0.z, w0.w, w1.x, w1.y, w1.z, w1.w,        \
                       w2.x, w2.y, w2.z, w2.w};                               \
        _Pragma("unroll")                                                     \
        for (int dx = 0; dx < ND; ++dx) {                                     \
            _Pragma("unroll")                                                 \
            for (int j = 0; j < TX; ++j)                                      \
                acc[dx][j] += a[j] * w[dx + j];                               \
        }                                                                     \
    }

    #define COMPUTE(BUFI)                                                     \
    if (isComp) {                                                             \
        const char* bb = (const char*)lds + (BUFI) * BUF_B;                   \
        FMACH(aof0, wb0)                                                      \
        FMACH(aof1, wb1)                                                      \
    }

    // body kc (wave-local, NO barrier):
    //   vmcnt(3): chunk kc's 3 DMAs landed (kc+1's 3 outstanding);
    //   COMPUTE(kc&1); lgkmcnt(0): own ds_reads retired -> safe to overwrite.
    #define BODY(BUFI, WN, DOISS)                                             \
        asm volatile("s_waitcnt vmcnt(" WN ")" ::: "memory");                 \
        __builtin_amdgcn_sched_barrier(0);                                    \
        COMPUTE(BUFI)                                                         \
        asm volatile("s_waitcnt lgkmcnt(0)" ::: "memory");                    \
        __builtin_amdgcn_sched_barrier(0);                                    \
        if (DOISS) { ISSUE(BUFI) }

    // ---- prologue: DMA chunks 0,1 into buffers 0,1 (6 outstanding)
    ISSUE(0)
    ISSUE(1)

    // ---- main loop: kc = 0..125 (body kc issues kc+2 into buffer kc&1)
    #pragma unroll 1
    for (int g = 0; g < 63; ++g) {
        BODY(0, "3", true)
        BODY(1, "3", true)
    }
    // ---- tail: kc = 126 (127 outstanding), kc = 127
    BODY(0, "3", false)
    BODY(1, "0", false)

    #undef BODY
    #undef COMPUTE
    #undef FMACH
    #undef ISSUE

    // ---- epilogue: OOB-dy rows output zeros (masked scale; staged clamped
    // garbage is finite real data, so 0-scale is exact)
    if (isComp) {
        const float m = rowOk ? (1.0f / (float)C_) : 0.f;
        float* outp = out + ((size_t)(b * NDISP + dy * ND) * H_ + y) * W_ + x0;
        #pragma unroll
        for (int dx = 0; dx < ND; ++dx) {
            float4 o = make_float4(acc[dx][0] * m, acc[dx][1] * m,
                                   acc[dx][2] * m, acc[dx][3] * m);
            *(float4*)(outp + dx * (H_ * W_)) = o;
        }
    }
}

extern "C" void kernel_launch(void* const* d_in, const int* in_sizes, int n_in,
                              void* d_out, int out_size, void* d_ws, size_t ws_size,
                              hipStream_t stream) {
    const float* in1 = (const float*)d_in[0];
    const float* in2 = (const float*)d_in[1];
    float* out = (float*)d_out;

    const int grid = B_ * H_ * 3 * 2;   // 4608 single-wave blocks (~16-18/CU)
    corr_hx_kernel<<<grid, NTHR, 0, stream>>>(in1, in2, out);
}